// Round 21
// baseline (57.371 us; speedup 1.0000x reference)
//
#include <hip/hip_runtime.h>
#include <math.h>

#define HW    9216      // 96*96
#define NPIX  18432     // B*HW
#define NKEY  8192

// ws layout (float units)
#define OFF_QPK  0                       // [NPIX][8]  : A-frag pack (Q), 2 x f32x4 of bf16 pairs
#define OFF_KPK  (OFF_QPK + NPIX*8)      // [NKEY][8]  : B-frag pack (K)
#define OFF_VT   (OFF_KPK + NKEY*8)      // [NKEY][4]  : v0,v1,v2,0
#define OFF_EEHS (OFF_VT + NKEY*4)       // [NPIX][8]  : EE0..2,S | HH0..2,pad
#define OFF_MM   (OFF_EEHS + NPIX*8)     // [288][2]   : per-wave S min,max
#define OFF_PART (OFF_MM + 576)          // [8][NPIX][4] : s, sv0, sv1, sv2

#if __has_builtin(__builtin_amdgcn_exp2f)
#define EXP2(x) __builtin_amdgcn_exp2f(x)
#else
#define EXP2(x) exp2f(x)
#endif

typedef float f32x2 __attribute__((ext_vector_type(2)));
typedef float f32x4 __attribute__((ext_vector_type(4)));
typedef short bf16x8 __attribute__((ext_vector_type(8)));
typedef unsigned u32x4 __attribute__((ext_vector_type(4)));

// ---- VOP3P packed-f32 (verified: all operands are 64-bit VGPR pairs, no op_sel) ----
__device__ __forceinline__ f32x2 pk_add(f32x2 a, f32x2 b){
    f32x2 d; asm("v_pk_add_f32 %0, %1, %2" : "=v"(d) : "v"(a), "v"(b)); return d;
}
__device__ __forceinline__ f32x2 pk_fma(f32x2 a, f32x2 b, f32x2 c){
    f32x2 d; asm("v_pk_fma_f32 %0, %1, %2, %3" : "=v"(d) : "v"(a), "v"(b), "v"(c)); return d;
}

__device__ __forceinline__ unsigned bf16rne(float x){
    unsigned b = __builtin_bit_cast(unsigned, x);
    return (b + 0x7FFFu + ((b >> 16) & 1u)) >> 16;
}
__device__ __forceinline__ float bf16tof(unsigned h){
    return __builtin_bit_cast(float, h << 16);
}

__device__ __forceinline__ float gelu_tanh(float x){
    float u = 0.7978845608028654f*(x + 0.044715f*x*x*x);
    return 0.5f*x*(1.0f + tanhf(u));
}

// ---------------- k1: fused prep. 72 blocks x 256 threads, 16x16 output tile each ----------------
__global__ __launch_bounds__(256) void k1_prep(
    const float* __restrict__ front, const float* __restrict__ back,
    const float* __restrict__ bg,
    const float* __restrict__ k_w,  const float* __restrict__ v_w,
    const float* __restrict__ mi_w1, const float* __restrict__ mi_b1,
    const float* __restrict__ mi_w2, const float* __restrict__ mi_b2,
    const float* __restrict__ q_w,
    const float* __restrict__ n1_g, const float* __restrict__ n1_b,
    const float* __restrict__ e_w,  const float* __restrict__ e_b,
    const float* __restrict__ f_w,  const float* __restrict__ f_b,
    const float* __restrict__ g_w,  const float* __restrict__ g_b,
    const float* __restrict__ h_w,  const float* __restrict__ h_b,
    float* __restrict__ ws)
{
    float* ws_qpk  = ws + OFF_QPK;
    float* ws_kpk  = ws + OFF_KPK;
    float* ws_eehs = ws + OFF_EEHS;
    float* ws_mm   = ws + OFF_MM;

    __shared__ float lds[6][484];        // 22x22 halo, planes: f0,f1,f2,b0,b1,b2

    int tid = threadIdx.x;
    int bid = blockIdx.x;                // 0..71
    int img = bid / 36;
    int t   = bid % 36;
    int ty  = (t / 6) * 16;
    int tx  = (t % 6) * 16;

    // ---------- key/value pack (blocks 0..31 handle 8192 keys) ----------
    if (bid < 32){
        int key = bid*256 + tid;
        float c0=bg[key], c1=bg[NKEY+key], c2=bg[2*NKEY+key];
        float kv3[3], vv3[3];
        #pragma unroll
        for (int i=0;i<3;i++){
            kv3[i] = k_w[i*3+0]*c0 + k_w[i*3+1]*c1 + k_w[i*3+2]*c2;
            vv3[i] = v_w[i*3+0]*c0 + v_w[i*3+1]*c1 + v_w[i*3+2]*c2;
        }
        unsigned kh[3], kl[3];
        #pragma unroll
        for (int i=0;i<3;i++){
            kh[i] = bf16rne(kv3[i]);
            kl[i] = bf16rne(kv3[i] - bf16tof(kh[i]));
        }
        // B-frag (QK^T) slots g0: [kh0,kh1,kh2,kl0,kl1,kl2,kh0,kh1]  g1: [kh2,0,...]
        unsigned u[8];
        u[0] = kh[0] | (kh[1]<<16);
        u[1] = kh[2] | (kl[0]<<16);
        u[2] = kl[1] | (kl[2]<<16);
        u[3] = kh[0] | (kh[1]<<16);
        u[4] = kh[2]; u[5]=0; u[6]=0; u[7]=0;
        f32x4* kp4 = (f32x4*)ws_kpk;
        kp4[(size_t)key*2+0] = __builtin_bit_cast(f32x4, *(const u32x4*)&u[0]);
        kp4[(size_t)key*2+1] = __builtin_bit_cast(f32x4, *(const u32x4*)&u[4]);
        ((f32x4*)(ws + OFF_VT))[key] = (f32x4){vv3[0], vv3[1], vv3[2], 0.0f};
    }

    const float* fbase = front + img*3*HW;
    const float* bbase = back  + img*3*HW;

    // ---------- stage 22x22 halo (zero-padded) for 6 planes ----------
    for (int i = tid; i < 484; i += 256){
        int hy = i / 22, hx = i - hy*22;
        int gy = ty + hy - 3, gx = tx + hx - 3;
        bool ok = ((unsigned)gy < 96u) && ((unsigned)gx < 96u);
        int off = gy*96 + gx;
        #pragma unroll
        for (int c=0;c<3;c++){
            lds[c  ][i] = ok ? fbase[c*HW+off] : 0.0f;
            lds[3+c][i] = ok ? bbase[c*HW+off] : 0.0f;
        }
    }
    __syncthreads();

    int ly = tid / 16, lx = tid - ly*16;
    int y  = ty + ly,  x  = tx + lx;
    int pos = y*96 + x;
    int pix = img*HW + pos;

    // ---------- 7x7 box stats from LDS ----------
    float s1f[3]={0,0,0}, s2f[3]={0,0,0}, s1b[3]={0,0,0}, s2b[3]={0,0,0};
    #pragma unroll
    for (int dy=0; dy<7; ++dy){
        int rb = (ly+dy)*22 + lx;
        #pragma unroll
        for (int dx=0; dx<7; ++dx){
            #pragma unroll
            for (int c=0;c<3;c++){
                float fv = lds[c  ][rb+dx];
                float bv = lds[3+c][rb+dx];
                s1f[c]+=fv; s2f[c]+=fv*fv;
                s1b[c]+=bv; s2b[c]+=bv*bv;
            }
        }
    }

    int ctr = (ly+3)*22 + (lx+3);
    float xnf[3], adain[3], bn[3], bval[3], fctr[3];
    #pragma unroll
    for (int c=0;c<3;c++){
        float mf = s1f[c]*(1.0f/49.0f);
        float vf = (s2f[c] - s1f[c]*s1f[c]*(1.0f/49.0f))*(1.0f/48.0f);
        float fv = lds[c][ctr];
        fctr[c] = fv;
        xnf[c] = (fv - mf)/(sqrtf(vf)+1e-8f);

        float mb = s1b[c]*(1.0f/49.0f);
        float vb = (s2b[c] - s1b[c]*s1b[c]*(1.0f/49.0f))*(1.0f/48.0f);
        float bb = lds[3+c][ctr];
        bval[c]  = bb;
        float stdb = sqrtf(vb);
        adain[c] = xnf[c]*stdb + mb;         // no eps on y_std
        bn[c]    = (bb - mb)/(stdb + 1e-8f);
    }

    float EE[3], FF[3], GG[3], HHv[3];
    #pragma unroll
    for (int i=0;i<3;i++){
        EE[i]  = e_w[i*3+0]*adain[0] + e_w[i*3+1]*adain[1] + e_w[i*3+2]*adain[2] + e_b[i];
        FF[i]  = f_w[i*3+0]*xnf[0]   + f_w[i*3+1]*xnf[1]   + f_w[i*3+2]*xnf[2]   + f_b[i];
        GG[i]  = g_w[i*3+0]*bn[0]    + g_w[i*3+1]*bn[1]    + g_w[i*3+2]*bn[2]    + g_b[i];
        HHv[i] = h_w[i*3+0]*bval[0]  + h_w[i*3+1]*bval[1]  + h_w[i*3+2]*bval[2]  + h_b[i];
    }
    float num = FF[0]*GG[0]+FF[1]*GG[1]+FF[2]*GG[2];
    float fn  = sqrtf(FF[0]*FF[0]+FF[1]*FF[1]+FF[2]*FF[2]);
    float gn  = sqrtf(GG[0]*GG[0]+GG[1]*GG[1]+GG[2]*GG[2]);
    float S   = num/(fn*gn);

    float4* eehs4 = (float4*)ws_eehs;
    eehs4[pix*2+0] = make_float4(EE[0],EE[1],EE[2],S);
    eehs4[pix*2+1] = make_float4(HHv[0],HHv[1],HHv[2],0.0f);

    // ---------- per-wave S min/max ----------
    float mn = S, mx = S;
    #pragma unroll
    for (int off=32; off>0; off>>=1){
        mn = fminf(mn, __shfl_xor(mn, off));
        mx = fmaxf(mx, __shfl_xor(mx, off));
    }
    if ((tid & 63) == 0){
        int entry = bid*4 + (tid>>6);
        ws_mm[entry*2+0]=mn; ws_mm[entry*2+1]=mx;
    }

    // ---------- token q : mlp_in -> ln -> q_w, pre-scaled by scale*log2e; bf16-split pack ----------
    float xt0 = fctr[0], xt1 = fctr[1], xt2 = fctr[2];
    float h6[6];
    #pragma unroll
    for (int i=0;i<6;i++){
        float a = mi_w1[i*3+0]*xt0 + mi_w1[i*3+1]*xt1 + mi_w1[i*3+2]*xt2 + mi_b1[i];
        h6[i] = gelu_tanh(a);
    }
    float x2[3];
    #pragma unroll
    for (int i=0;i<3;i++){
        float a = mi_b2[i];
        #pragma unroll
        for (int k=0;k<6;k++) a += mi_w2[i*6+k]*h6[k];
        x2[i]=a;
    }
    float m  = (x2[0]+x2[1]+x2[2])*(1.0f/3.0f);
    float d0 = x2[0]-m, d1 = x2[1]-m, d2 = x2[2]-m;
    float var = (d0*d0+d1*d1+d2*d2)*(1.0f/3.0f);
    float inv = 1.0f/sqrtf(var+1e-5f);
    float xn0 = d0*inv*n1_g[0]+n1_b[0];
    float xn1 = d1*inv*n1_g[1]+n1_b[1];
    float xn2 = d2*inv*n1_g[2]+n1_b[2];
    const float qs = 0.5773502691896258f * 1.4426950408889634f; // d^-0.5 * log2(e)
    float qv[3];
    qv[0] = (q_w[0]*xn0 + q_w[1]*xn1 + q_w[2]*xn2)*qs;
    qv[1] = (q_w[3]*xn0 + q_w[4]*xn1 + q_w[5]*xn2)*qs;
    qv[2] = (q_w[6]*xn0 + q_w[7]*xn1 + q_w[8]*xn2)*qs;

    unsigned qh[3], ql[3];
    #pragma unroll
    for (int i=0;i<3;i++){
        qh[i] = bf16rne(qv[i]);
        ql[i] = bf16rne(qv[i] - bf16tof(qh[i]));
    }
    // A-frag (QK^T) slots g0: [qh0,qh1,qh2,qh0,qh1,qh2,ql0,ql1]  g1: [ql2,0,...]
    unsigned u[8];
    u[0] = qh[0] | (qh[1]<<16);
    u[1] = qh[2] | (qh[0]<<16);
    u[2] = qh[1] | (qh[2]<<16);
    u[3] = ql[0] | (ql[1]<<16);
    u[4] = ql[2]; u[5]=0; u[6]=0; u[7]=0;
    f32x4* qp4 = (f32x4*)ws_qpk;
    qp4[(size_t)pix*2+0] = __builtin_bit_cast(f32x4, *(const u32x4*)&u[0]);
    qp4[(size_t)pix*2+1] = __builtin_bit_cast(f32x4, *(const u32x4*)&u[4]);
}

// ---------------- k2: MFMA QK^T + pk PV, 2 q-tiles/wave, NC=8. 1152 blocks x 256 ----------------
// block b: key-eighth kq=b&7 (1024 keys), q-group qg=b>>3 (0..143);
// wave w: q-tiles qg*8+w*2+{0,1}. Per step: 1 frag read + 1 v read feed 2 MFMAs + 2 PV sets.
#define RED4(vv, mm) { vv.x += __shfl_xor(vv.x,mm); vv.y += __shfl_xor(vv.y,mm); \
                       vv.z += __shfl_xor(vv.z,mm); vv.w += __shfl_xor(vv.w,mm); }

__global__ __launch_bounds__(256) void k2_attn(const float* __restrict__ ws)
{
    const f32x4* qpk = (const f32x4*)(ws + OFF_QPK);
    const f32x4* kpk = (const f32x4*)(ws + OFF_KPK);
    const f32x4* vt  = (const f32x4*)(ws + OFF_VT);
    f32x4* part      = (f32x4*)(ws + OFF_PART);

    __shared__ f32x4 lkp[512];    // 256 keys x 2 frags (8KB)
    __shared__ f32x4 lv[256];     // 256 keys x (v0,v1,v2,0) (4KB)

    int tid  = threadIdx.x;
    int bid  = blockIdx.x;
    int kq   = bid & 7;           // key-eighth (1024 keys)
    int qg   = bid >> 3;          // 0..143
    int wave = tid >> 6, lane = tid & 63;
    int qt0  = qg*8 + wave*2;     // first of two q-tiles
    int g = lane >> 4, col = lane & 15;

    bf16x8 af0 = {0,0,0,0,0,0,0,0}, af1 = {0,0,0,0,0,0,0,0};
    if (g < 2){
        af0 = __builtin_bit_cast(bf16x8, qpk[(size_t)(qt0*16 + col)*2 + g]);
        af1 = __builtin_bit_cast(bf16x8, qpk[(size_t)((qt0+1)*16 + col)*2 + g]);
    }

    f32x2 slo0={0,0}, shi0={0,0}, a0lo0={0,0}, a0hi0={0,0}, a1lo0={0,0}, a1hi0={0,0}, a2lo0={0,0}, a2hi0={0,0};
    f32x2 slo1={0,0}, shi1={0,0}, a0lo1={0,0}, a0hi1={0,0}, a1lo1={0,0}, a1hi1={0,0}, a2lo1={0,0}, a2hi1={0,0};

    const f32x4* kpbase = kpk + ((size_t)kq*1024)*2;
    const f32x4* vbase  = vt + kq*1024;

    for (int chunk=0; chunk<4; ++chunk){
        for (int i=tid; i<512; i+=256) lkp[i] = kpbase[chunk*512 + i];
        if (tid < 256) lv[tid] = vbase[chunk*256 + tid];
        __syncthreads();
        #pragma unroll 4
        for (int st=0; st<16; ++st){
            bf16x8 bfrag = {0,0,0,0,0,0,0,0};
            if (g < 2)
                bfrag = __builtin_bit_cast(bf16x8, lkp[(st*16+col)*2 + g]);
            f32x4 v = lv[st*16+col];
            f32x4 S0 = __builtin_amdgcn_mfma_f32_16x16x32_bf16(af0, bfrag, (f32x4){0,0,0,0}, 0, 0, 0);
            f32x4 S1 = __builtin_amdgcn_mfma_f32_16x16x32_bf16(af1, bfrag, (f32x4){0,0,0,0}, 0, 0, 0);
            f32x2 vx = (f32x2){v.x, v.x};
            f32x2 vy = (f32x2){v.y, v.y};
            f32x2 vz = (f32x2){v.z, v.z};
            f32x2 plo0, phi0, plo1, phi1;
            plo0.x = EXP2(S0.x); plo0.y = EXP2(S0.y);
            phi0.x = EXP2(S0.z); phi0.y = EXP2(S0.w);
            plo1.x = EXP2(S1.x); plo1.y = EXP2(S1.y);
            phi1.x = EXP2(S1.z); phi1.y = EXP2(S1.w);
            slo0  = pk_add(slo0, plo0);      shi0  = pk_add(shi0, phi0);
            a0lo0 = pk_fma(plo0, vx, a0lo0); a0hi0 = pk_fma(phi0, vx, a0hi0);
            a1lo0 = pk_fma(plo0, vy, a1lo0); a1hi0 = pk_fma(phi0, vy, a1hi0);
            a2lo0 = pk_fma(plo0, vz, a2lo0); a2hi0 = pk_fma(phi0, vz, a2hi0);
            slo1  = pk_add(slo1, plo1);      shi1  = pk_add(shi1, phi1);
            a0lo1 = pk_fma(plo1, vx, a0lo1); a0hi1 = pk_fma(phi1, vx, a0hi1);
            a1lo1 = pk_fma(plo1, vy, a1lo1); a1hi1 = pk_fma(phi1, vy, a1hi1);
            a2lo1 = pk_fma(plo1, vz, a2lo1); a2hi1 = pk_fma(phi1, vz, a2hi1);
        }
        __syncthreads();
    }

    f32x4 s0_  = {slo0.x, slo0.y, shi0.x, shi0.y};
    f32x4 a00_ = {a0lo0.x, a0lo0.y, a0hi0.x, a0hi0.y};
    f32x4 a10_ = {a1lo0.x, a1lo0.y, a1hi0.x, a1hi0.y};
    f32x4 a20_ = {a2lo0.x, a2lo0.y, a2hi0.x, a2hi0.y};
    f32x4 s1_  = {slo1.x, slo1.y, shi1.x, shi1.y};
    f32x4 a01_ = {a0lo1.x, a0lo1.y, a0hi1.x, a0hi1.y};
    f32x4 a11_ = {a1lo1.x, a1lo1.y, a1hi1.x, a1hi1.y};
    f32x4 a21_ = {a2lo1.x, a2lo1.y, a2hi1.x, a2hi1.y};

    RED4(s0_, 8) RED4(a00_, 8) RED4(a10_, 8) RED4(a20_, 8)
    RED4(s0_, 4) RED4(a00_, 4) RED4(a10_, 4) RED4(a20_, 4)
    RED4(s0_, 2) RED4(a00_, 2) RED4(a10_, 2) RED4(a20_, 2)
    RED4(s0_, 1) RED4(a00_, 1) RED4(a10_, 1) RED4(a20_, 1)
    RED4(s1_, 8) RED4(a01_, 8) RED4(a11_, 8) RED4(a21_, 8)
    RED4(s1_, 4) RED4(a01_, 4) RED4(a11_, 4) RED4(a21_, 4)
    RED4(s1_, 2) RED4(a01_, 2) RED4(a11_, 2) RED4(a21_, 2)
    RED4(s1_, 1) RED4(a01_, 1) RED4(a11_, 1) RED4(a21_, 1)

    f32x4* dst0 = part + (size_t)kq*NPIX + qt0*16 + g*4;
    f32x4* dst1 = dst0 + 16;
    if      (col==0){ dst0[0] = (f32x4){s0_.x, a00_.x, a10_.x, a20_.x};
                      dst1[0] = (f32x4){s1_.x, a01_.x, a11_.x, a21_.x}; }
    else if (col==1){ dst0[1] = (f32x4){s0_.y, a00_.y, a10_.y, a20_.y};
                      dst1[1] = (f32x4){s1_.y, a01_.y, a11_.y, a21_.y}; }
    else if (col==2){ dst0[2] = (f32x4){s0_.z, a00_.z, a10_.z, a20_.z};
                      dst1[2] = (f32x4){s1_.z, a01_.z, a11_.z, a21_.z}; }
    else if (col==3){ dst0[3] = (f32x4){s0_.w, a00_.w, a10_.w, a20_.w};
                      dst1[3] = (f32x4){s1_.w, a01_.w, a11_.w, a21_.w}; }
}

// ---------------- k3: 288 blocks x 256 threads; 4 threads/pixel merge (NC=8), wave0 epilogue ----------------
template<int NC_T>
__global__ __launch_bounds__(256) void k3_final(
    const float* __restrict__ ws,
    const float* __restrict__ mo_w1, const float* __restrict__ mo_b1,
    const float* __restrict__ mo_w2, const float* __restrict__ mo_b2,
    const float* __restrict__ n2_g,  const float* __restrict__ n2_b,
    const float* __restrict__ fuse_w,const float* __restrict__ fuse_b,
    float* __restrict__ out)
{
    const float* ws_eehs = ws + OFF_EEHS;
    const float* ws_mm   = ws + OFF_MM;
    const float* ws_part = ws + OFF_PART;

    int tid = threadIdx.x;
    int g   = tid >> 6;                 // chunk group 0..3
    int lp  = tid & 63;                 // pixel lane within block
    int pixbase = blockIdx.x*64;
    int pix = pixbase + lp;
    int b   = (pix >= HW) ? 1 : 0;      // uniform per block (9216 % 64 == 0)

    // ---------- partial merge: each thread NC_T/4 chunks for its pixel ----------
    constexpr int CPG = NC_T/4;
    float s=0.0f, a0=0.0f, a1=0.0f, a2=0.0f;
    const f32x4* part4 = (const f32x4*)ws_part;
    #pragma unroll
    for (int c=g*CPG; c<(g+1)*CPG; ++c){
        f32x4 p = part4[(size_t)c*NPIX + pix];
        s+=p.x; a0+=p.y; a1+=p.z; a2+=p.w;
    }
    __shared__ f32x4 red[256];
    red[tid] = (f32x4){s,a0,a1,a2};

    // ---------- batch S min/max (144 wave entries) ----------
    __shared__ float wmn[4], wmx[4];
    float mn = INFINITY, mx = -INFINITY;
    if (tid < 144){
        mn = ws_mm[(b*144+tid)*2+0];
        mx = ws_mm[(b*144+tid)*2+1];
    }
    #pragma unroll
    for (int off=32; off>0; off>>=1){
        mn = fminf(mn, __shfl_xor(mn, off));
        mx = fmaxf(mx, __shfl_xor(mx, off));
    }
    if ((tid & 63) == 0){ wmn[tid>>6]=mn; wmx[tid>>6]=mx; }
    __syncthreads();

    if (tid < 64){
        mn = fminf(fminf(wmn[0],wmn[1]), fminf(wmn[2],wmn[3]));
        mx = fmaxf(fmaxf(wmx[0],wmx[1]), fmaxf(wmx[2],wmx[3]));

        f32x4 p0 = red[tid], p1 = red[64+tid], p2 = red[128+tid], p3 = red[192+tid];
        s  = p0.x+p1.x+p2.x+p3.x;
        a0 = p0.y+p1.y+p2.y+p3.y;
        a1 = p0.z+p1.z+p2.z+p3.z;
        a2 = p0.w+p1.w+p2.w+p3.w;
        float invs = 1.0f/s;
        float xa0 = a0*invs, xa1 = a1*invs, xa2 = a2*invs;

        // mlp_out
        float h6[6];
        #pragma unroll
        for (int i=0;i<6;i++){
            float a = mo_w1[i*3+0]*xa0 + mo_w1[i*3+1]*xa1 + mo_w1[i*3+2]*xa2 + mo_b1[i];
            h6[i] = gelu_tanh(a);
        }
        float y[3];
        #pragma unroll
        for (int i=0;i<3;i++){
            float a = mo_b2[i];
            #pragma unroll
            for (int k=0;k<6;k++) a += mo_w2[i*6+k]*h6[k];
            y[i]=a;
        }
        float m  = (y[0]+y[1]+y[2])*(1.0f/3.0f);
        float d0 = y[0]-m, d1 = y[1]-m, d2 = y[2]-m;
        float var = (d0*d0+d1*d1+d2*d2)*(1.0f/3.0f);
        float inv = 1.0f/sqrtf(var+1e-5f);
        float t0 = d0*inv*n2_g[0]+n2_b[0];
        float t1 = d1*inv*n2_g[1]+n2_b[1];
        float t2 = d2*inv*n2_g[2]+n2_b[2];

        // PSF: S_n normalize + blend
        float4 e  = ((const float4*)ws_eehs)[pix*2+0];   // EE, S
        float4 hh = ((const float4*)ws_eehs)[pix*2+1];   // HH
        float Sn = (e.w - mn)/(mx - mn);
        float f0 = Sn*e.x + (1.0f-Sn)*hh.x;
        float f1 = Sn*e.y + (1.0f-Sn)*hh.y;
        float f2 = Sn*e.z + (1.0f-Sn)*hh.z;

        int pos = pix - b*HW;
        #pragma unroll
        for (int o=0;o<3;o++){
            float val = fuse_b[o]
                      + fuse_w[o*6+0]*t0 + fuse_w[o*6+1]*t1 + fuse_w[o*6+2]*t2
                      + fuse_w[o*6+3]*f0 + fuse_w[o*6+4]*f1 + fuse_w[o*6+5]*f2;
            out[(b*3+o)*HW + pos] = val;
        }
    }
}

extern "C" void kernel_launch(void* const* d_in, const int* in_sizes, int n_in,
                              void* d_out, int out_size, void* d_ws, size_t ws_size,
                              hipStream_t stream) {
    const float* front  = (const float*)d_in[0];
    const float* back   = (const float*)d_in[1];
    // d_in[2] = mask (unused by reference)
    const float* bg     = (const float*)d_in[3];
    const float* mi_w1  = (const float*)d_in[4];
    const float* mi_b1  = (const float*)d_in[5];
    const float* mi_w2  = (const float*)d_in[6];
    const float* mi_b2  = (const float*)d_in[7];
    const float* q_w    = (const float*)d_in[8];
    const float* k_w    = (const float*)d_in[9];
    const float* v_w    = (const float*)d_in[10];
    const float* mo_w1  = (const float*)d_in[11];
    const float* mo_b1  = (const float*)d_in[12];
    const float* mo_w2  = (const float*)d_in[13];
    const float* mo_b2  = (const float*)d_in[14];
    const float* n1_g   = (const float*)d_in[15];
    const float* n1_b   = (const float*)d_in[16];
    const float* n2_g   = (const float*)d_in[17];
    const float* n2_b   = (const float*)d_in[18];
    const float* e_w    = (const float*)d_in[19];
    const float* e_b    = (const float*)d_in[20];
    const float* f_w    = (const float*)d_in[21];
    const float* f_b    = (const float*)d_in[22];
    const float* g_w    = (const float*)d_in[23];
    const float* g_b    = (const float*)d_in[24];
    const float* h_w    = (const float*)d_in[25];
    const float* h_b    = (const float*)d_in[26];
    const float* fuse_w = (const float*)d_in[27];
    const float* fuse_b = (const float*)d_in[28];

    float* ws  = (float*)d_ws;
    float* out = (float*)d_out;

    k1_prep<<<dim3(72), 256, 0, stream>>>(
        front, back, bg, k_w, v_w, mi_w1, mi_b1, mi_w2, mi_b2, q_w,
        n1_g, n1_b, e_w, e_b, f_w, f_b, g_w, g_b, h_w, h_b, ws);

    k2_attn<<<dim3(1152), 256, 0, stream>>>(ws);

    k3_final<8><<<dim3(NPIX/64), 256, 0, stream>>>(
        ws, mo_w1, mo_b1, mo_w2, mo_b2, n2_g, n2_b, fuse_w, fuse_b, out);
}

// Round 22
// 50.126 us; speedup vs baseline: 1.1445x; 1.1445x over previous
//
#include <hip/hip_runtime.h>
#include <math.h>

#define HW    9216      // 96*96
#define NPIX  18432     // B*HW
#define NKEY  8192

// ws layout (float units)
#define OFF_QPK  0                       // [NPIX][8]  : A-frag pack (Q), 2 x f32x4 of bf16 pairs
#define OFF_KPK  (OFF_QPK + NPIX*8)      // [NKEY][8]  : B-frag pack (K)
#define OFF_VT   (OFF_KPK + NKEY*8)      // [NKEY][4]  : v0,v1,v2,0
#define OFF_EEHS (OFF_VT + NKEY*4)       // [NPIX][8]  : EE0..2,S | HH0..2,pad
#define OFF_MM   (OFF_EEHS + NPIX*8)     // [288][2]   : per-block S min,max (288 blocks)
#define OFF_PART (OFF_MM + 576)          // [8][NPIX][4] : s, sv0, sv1, sv2

#if __has_builtin(__builtin_amdgcn_exp2f)
#define EXP2(x) __builtin_amdgcn_exp2f(x)
#else
#define EXP2(x) exp2f(x)
#endif

typedef float f32x4 __attribute__((ext_vector_type(4)));
typedef short bf16x8 __attribute__((ext_vector_type(8)));
typedef unsigned u32x4 __attribute__((ext_vector_type(4)));

__device__ __forceinline__ unsigned bf16rne(float x){
    unsigned b = __builtin_bit_cast(unsigned, x);
    return (b + 0x7FFFu + ((b >> 16) & 1u)) >> 16;
}
__device__ __forceinline__ float bf16tof(unsigned h){
    return __builtin_bit_cast(float, h << 16);
}

__device__ __forceinline__ float gelu_tanh(float x){
    float u = 0.7978845608028654f*(x + 0.044715f*x*x*x);
    return 0.5f*x*(1.0f + tanhf(u));
}

// ---------------- k1: fused prep. 288 blocks x 256 threads, 8x8 tile, 4 threads/pixel ----------------
__global__ __launch_bounds__(256) void k1_prep(
    const float* __restrict__ front, const float* __restrict__ back,
    const float* __restrict__ bg,
    const float* __restrict__ k_w,  const float* __restrict__ v_w,
    const float* __restrict__ mi_w1, const float* __restrict__ mi_b1,
    const float* __restrict__ mi_w2, const float* __restrict__ mi_b2,
    const float* __restrict__ q_w,
    const float* __restrict__ n1_g, const float* __restrict__ n1_b,
    const float* __restrict__ e_w,  const float* __restrict__ e_b,
    const float* __restrict__ f_w,  const float* __restrict__ f_b,
    const float* __restrict__ g_w,  const float* __restrict__ g_b,
    const float* __restrict__ h_w,  const float* __restrict__ h_b,
    float* __restrict__ ws)
{
    float* ws_qpk  = ws + OFF_QPK;
    float* ws_kpk  = ws + OFF_KPK;
    float* ws_eehs = ws + OFF_EEHS;
    float* ws_mm   = ws + OFF_MM;

    __shared__ float lds[6][196];      // 14x14 halo, planes: f0,f1,f2,b0,b1,b2
    __shared__ float red[12][256];     // per-thread box-sum partials (transposed, conflict-free)

    int tid = threadIdx.x;
    int bid = blockIdx.x;              // 0..287
    int img = bid / 144;
    int t   = bid % 144;
    int ty  = (t / 12) * 8;
    int tx  = (t % 12) * 8;

    // ---------- key/value pack (blocks 0..31 handle 8192 keys) ----------
    if (bid < 32){
        int key = bid*256 + tid;
        float c0=bg[key], c1=bg[NKEY+key], c2=bg[2*NKEY+key];
        float kv3[3], vv3[3];
        #pragma unroll
        for (int i=0;i<3;i++){
            kv3[i] = k_w[i*3+0]*c0 + k_w[i*3+1]*c1 + k_w[i*3+2]*c2;
            vv3[i] = v_w[i*3+0]*c0 + v_w[i*3+1]*c1 + v_w[i*3+2]*c2;
        }
        unsigned kh[3], kl[3];
        #pragma unroll
        for (int i=0;i<3;i++){
            kh[i] = bf16rne(kv3[i]);
            kl[i] = bf16rne(kv3[i] - bf16tof(kh[i]));
        }
        // B-frag (QK^T) slots g0: [kh0,kh1,kh2,kl0,kl1,kl2,kh0,kh1]  g1: [kh2,0,...]
        unsigned u[8];
        u[0] = kh[0] | (kh[1]<<16);
        u[1] = kh[2] | (kl[0]<<16);
        u[2] = kl[1] | (kl[2]<<16);
        u[3] = kh[0] | (kh[1]<<16);
        u[4] = kh[2]; u[5]=0; u[6]=0; u[7]=0;
        f32x4* kp4 = (f32x4*)ws_kpk;
        kp4[(size_t)key*2+0] = __builtin_bit_cast(f32x4, *(const u32x4*)&u[0]);
        kp4[(size_t)key*2+1] = __builtin_bit_cast(f32x4, *(const u32x4*)&u[4]);
        ((f32x4*)(ws + OFF_VT))[key] = (f32x4){vv3[0], vv3[1], vv3[2], 0.0f};
    }

    const float* fbase = front + img*3*HW;
    const float* bbase = back  + img*3*HW;

    // ---------- stage 14x14 halo (zero-padded) for 6 planes ----------
    for (int i = tid; i < 196; i += 256){
        int hy = i / 14, hx = i - hy*14;
        int gy = ty + hy - 3, gx = tx + hx - 3;
        bool ok = ((unsigned)gy < 96u) && ((unsigned)gx < 96u);
        int off = gy*96 + gx;
        #pragma unroll
        for (int c=0;c<3;c++){
            lds[c  ][i] = ok ? fbase[c*HW+off] : 0.0f;
            lds[3+c][i] = ok ? bbase[c*HW+off] : 0.0f;
        }
    }
    __syncthreads();

    int p  = tid & 63;                 // pixel 0..63
    int qd = tid >> 6;                 // quadrant 0..3 (window rows {0,1},{2,3},{4,5},{6})
    int ly = p >> 3, lx = p & 7;

    // ---------- partial 7x7 box sums (rows r0..r0+nr-1 of the window) ----------
    {
        float s1f[3]={0,0,0}, s2f[3]={0,0,0}, s1b[3]={0,0,0}, s2b[3]={0,0,0};
        int r0 = qd*2;
        int nr = (qd < 3) ? 2 : 1;
        for (int rr=0; rr<nr; ++rr){
            int rb = (ly + r0 + rr)*14 + lx;
            #pragma unroll
            for (int dx=0; dx<7; ++dx){
                #pragma unroll
                for (int c=0;c<3;c++){
                    float fv = lds[c  ][rb+dx];
                    float bv = lds[3+c][rb+dx];
                    s1f[c]+=fv; s2f[c]+=fv*fv;
                    s1b[c]+=bv; s2b[c]+=bv*bv;
                }
            }
        }
        #pragma unroll
        for (int c=0;c<3;c++){
            red[c  ][tid] = s1f[c];
            red[3+c][tid] = s2f[c];
            red[6+c][tid] = s1b[c];
            red[9+c][tid] = s2b[c];
        }
    }
    __syncthreads();

    if (tid < 64){
        // combine 4 quadrant partials
        float s1f[3]={0,0,0}, s2f[3]={0,0,0}, s1b[3]={0,0,0}, s2b[3]={0,0,0};
        #pragma unroll
        for (int q2=0; q2<4; ++q2){
            int src = p + q2*64;
            #pragma unroll
            for (int c=0;c<3;c++){
                s1f[c] += red[c  ][src];
                s2f[c] += red[3+c][src];
                s1b[c] += red[6+c][src];
                s2b[c] += red[9+c][src];
            }
        }

        int ctr = (ly+3)*14 + (lx+3);
        int pos = (ty+ly)*96 + (tx+lx);
        int pix = img*HW + pos;

        float xnf[3], adain[3], bn[3], bval[3], fctr[3];
        #pragma unroll
        for (int c=0;c<3;c++){
            float mf = s1f[c]*(1.0f/49.0f);
            float vf = (s2f[c] - s1f[c]*s1f[c]*(1.0f/49.0f))*(1.0f/48.0f);
            float fv = lds[c][ctr];
            fctr[c] = fv;
            xnf[c] = (fv - mf)/(sqrtf(vf)+1e-8f);

            float mb = s1b[c]*(1.0f/49.0f);
            float vb = (s2b[c] - s1b[c]*s1b[c]*(1.0f/49.0f))*(1.0f/48.0f);
            float bb = lds[3+c][ctr];
            bval[c]  = bb;
            float stdb = sqrtf(vb);
            adain[c] = xnf[c]*stdb + mb;         // no eps on y_std
            bn[c]    = (bb - mb)/(stdb + 1e-8f);
        }

        float EE[3], FF[3], GG[3], HHv[3];
        #pragma unroll
        for (int i=0;i<3;i++){
            EE[i]  = e_w[i*3+0]*adain[0] + e_w[i*3+1]*adain[1] + e_w[i*3+2]*adain[2] + e_b[i];
            FF[i]  = f_w[i*3+0]*xnf[0]   + f_w[i*3+1]*xnf[1]   + f_w[i*3+2]*xnf[2]   + f_b[i];
            GG[i]  = g_w[i*3+0]*bn[0]    + g_w[i*3+1]*bn[1]    + g_w[i*3+2]*bn[2]    + g_b[i];
            HHv[i] = h_w[i*3+0]*bval[0]  + h_w[i*3+1]*bval[1]  + h_w[i*3+2]*bval[2]  + h_b[i];
        }
        float num = FF[0]*GG[0]+FF[1]*GG[1]+FF[2]*GG[2];
        float fn  = sqrtf(FF[0]*FF[0]+FF[1]*FF[1]+FF[2]*FF[2]);
        float gn  = sqrtf(GG[0]*GG[0]+GG[1]*GG[1]+GG[2]*GG[2]);
        float S   = num/(fn*gn);

        float4* eehs4 = (float4*)ws_eehs;
        eehs4[pix*2+0] = make_float4(EE[0],EE[1],EE[2],S);
        eehs4[pix*2+1] = make_float4(HHv[0],HHv[1],HHv[2],0.0f);

        // per-block S min/max (one wave active)
        float mn = S, mx = S;
        #pragma unroll
        for (int off=32; off>0; off>>=1){
            mn = fminf(mn, __shfl_xor(mn, off));
            mx = fmaxf(mx, __shfl_xor(mx, off));
        }
        if (p == 0){ ws_mm[bid*2+0]=mn; ws_mm[bid*2+1]=mx; }

        // token q : mlp_in -> ln -> q_w, pre-scaled by scale*log2e; bf16-split pack
        float xt0 = fctr[0], xt1 = fctr[1], xt2 = fctr[2];
        float h6[6];
        #pragma unroll
        for (int i=0;i<6;i++){
            float a = mi_w1[i*3+0]*xt0 + mi_w1[i*3+1]*xt1 + mi_w1[i*3+2]*xt2 + mi_b1[i];
            h6[i] = gelu_tanh(a);
        }
        float x2[3];
        #pragma unroll
        for (int i=0;i<3;i++){
            float a = mi_b2[i];
            #pragma unroll
            for (int k=0;k<6;k++) a += mi_w2[i*6+k]*h6[k];
            x2[i]=a;
        }
        float m  = (x2[0]+x2[1]+x2[2])*(1.0f/3.0f);
        float d0 = x2[0]-m, d1 = x2[1]-m, d2 = x2[2]-m;
        float var = (d0*d0+d1*d1+d2*d2)*(1.0f/3.0f);
        float inv = 1.0f/sqrtf(var+1e-5f);
        float xn0 = d0*inv*n1_g[0]+n1_b[0];
        float xn1 = d1*inv*n1_g[1]+n1_b[1];
        float xn2 = d2*inv*n1_g[2]+n1_b[2];
        const float qs = 0.5773502691896258f * 1.4426950408889634f; // d^-0.5 * log2(e)
        float qv[3];
        qv[0] = (q_w[0]*xn0 + q_w[1]*xn1 + q_w[2]*xn2)*qs;
        qv[1] = (q_w[3]*xn0 + q_w[4]*xn1 + q_w[5]*xn2)*qs;
        qv[2] = (q_w[6]*xn0 + q_w[7]*xn1 + q_w[8]*xn2)*qs;

        unsigned qh[3], ql[3];
        #pragma unroll
        for (int i=0;i<3;i++){
            qh[i] = bf16rne(qv[i]);
            ql[i] = bf16rne(qv[i] - bf16tof(qh[i]));
        }
        // A-frag (QK^T) slots g0: [qh0,qh1,qh2,qh0,qh1,qh2,ql0,ql1]  g1: [ql2,0,...]
        unsigned u[8];
        u[0] = qh[0] | (qh[1]<<16);
        u[1] = qh[2] | (qh[0]<<16);
        u[2] = qh[1] | (qh[2]<<16);
        u[3] = ql[0] | (ql[1]<<16);
        u[4] = ql[2]; u[5]=0; u[6]=0; u[7]=0;
        f32x4* qp4 = (f32x4*)ws_qpk;
        qp4[(size_t)pix*2+0] = __builtin_bit_cast(f32x4, *(const u32x4*)&u[0]);
        qp4[(size_t)pix*2+1] = __builtin_bit_cast(f32x4, *(const u32x4*)&u[4]);
    }
}

// ---------------- k2: MFMA QK^T + VALU PV. 2304 blocks x 256 (4 waves), 12KB LDS (r18-verified) ----------------
#define RED4(vv, mm) { vv.x += __shfl_xor(vv.x,mm); vv.y += __shfl_xor(vv.y,mm); \
                       vv.z += __shfl_xor(vv.z,mm); vv.w += __shfl_xor(vv.w,mm); }

__global__ __launch_bounds__(256) void k2_attn(const float* __restrict__ ws)
{
    const f32x4* qpk = (const f32x4*)(ws + OFF_QPK);
    const f32x4* kpk = (const f32x4*)(ws + OFF_KPK);
    const f32x4* vt  = (const f32x4*)(ws + OFF_VT);
    f32x4* part      = (f32x4*)(ws + OFF_PART);

    __shared__ f32x4 lkp[512];    // 256 keys x 2 frags (8KB)
    __shared__ f32x4 lv[256];     // 256 keys x (v0,v1,v2,0) (4KB)

    int tid  = threadIdx.x;
    int bid  = blockIdx.x;
    int kq   = bid & 7;           // key-eighth (1024 keys)
    int qg   = bid >> 3;          // 0..287
    int wave = tid >> 6, lane = tid & 63;
    int qtile = qg*4 + wave;
    int g = lane >> 4, col = lane & 15;

    bf16x8 afrag = {0,0,0,0,0,0,0,0};
    if (g < 2)
        afrag = __builtin_bit_cast(bf16x8, qpk[(size_t)(qtile*16 + col)*2 + g]);

    f32x4 s_ = {0,0,0,0}, a0_ = {0,0,0,0}, a1_ = {0,0,0,0}, a2_ = {0,0,0,0};

    const f32x4* kpbase = kpk + ((size_t)kq*1024)*2;
    const f32x4* vbase  = vt + kq*1024;

    for (int chunk=0; chunk<4; ++chunk){
        for (int i=tid; i<512; i+=256) lkp[i] = kpbase[chunk*512 + i];
        if (tid < 256)             lv[tid] = vbase[chunk*256 + tid];
        __syncthreads();
        #pragma unroll 4
        for (int st=0; st<16; ++st){
            bf16x8 bfrag = {0,0,0,0,0,0,0,0};
            if (g < 2)
                bfrag = __builtin_bit_cast(bf16x8, lkp[(st*16+col)*2 + g]);
            f32x4 S = __builtin_amdgcn_mfma_f32_16x16x32_bf16(afrag, bfrag, (f32x4){0,0,0,0}, 0, 0, 0);
            f32x4 v = lv[st*16+col];
            f32x4 p;
            p.x = EXP2(S.x); p.y = EXP2(S.y); p.z = EXP2(S.z); p.w = EXP2(S.w);
            s_  += p;
            a0_ += p * v.x;
            a1_ += p * v.y;
            a2_ += p * v.z;
        }
        __syncthreads();
    }

    RED4(s_, 8) RED4(a0_, 8) RED4(a1_, 8) RED4(a2_, 8)
    RED4(s_, 4) RED4(a0_, 4) RED4(a1_, 4) RED4(a2_, 4)
    RED4(s_, 2) RED4(a0_, 2) RED4(a1_, 2) RED4(a2_, 2)
    RED4(s_, 1) RED4(a0_, 1) RED4(a1_, 1) RED4(a2_, 1)

    int qbase = qtile*16 + g*4;
    f32x4* dst = part + (size_t)kq*NPIX + qbase;
    if      (col==0) dst[0] = (f32x4){s_.x, a0_.x, a1_.x, a2_.x};
    else if (col==1) dst[1] = (f32x4){s_.y, a0_.y, a1_.y, a2_.y};
    else if (col==2) dst[2] = (f32x4){s_.z, a0_.z, a1_.z, a2_.z};
    else if (col==3) dst[3] = (f32x4){s_.w, a0_.w, a1_.w, a2_.w};
}

// ---------------- k3: 288 blocks x 256 threads; 4 threads/pixel merge (NC=8), wave0 epilogue ----------------
template<int NC_T>
__global__ __launch_bounds__(256) void k3_final(
    const float* __restrict__ ws,
    const float* __restrict__ mo_w1, const float* __restrict__ mo_b1,
    const float* __restrict__ mo_w2, const float* __restrict__ mo_b2,
    const float* __restrict__ n2_g,  const float* __restrict__ n2_b,
    const float* __restrict__ fuse_w,const float* __restrict__ fuse_b,
    float* __restrict__ out)
{
    const float* ws_eehs = ws + OFF_EEHS;
    const float* ws_mm   = ws + OFF_MM;
    const float* ws_part = ws + OFF_PART;

    int tid = threadIdx.x;
    int g   = tid >> 6;                 // chunk group 0..3
    int lp  = tid & 63;                 // pixel lane within block
    int pixbase = blockIdx.x*64;
    int pix = pixbase + lp;
    int b   = (pix >= HW) ? 1 : 0;      // uniform per block (9216 % 64 == 0)

    // ---------- partial merge: each thread NC_T/4 chunks for its pixel ----------
    constexpr int CPG = NC_T/4;
    float s=0.0f, a0=0.0f, a1=0.0f, a2=0.0f;
    const f32x4* part4 = (const f32x4*)ws_part;
    #pragma unroll
    for (int c=g*CPG; c<(g+1)*CPG; ++c){
        f32x4 p = part4[(size_t)c*NPIX + pix];
        s+=p.x; a0+=p.y; a1+=p.z; a2+=p.w;
    }
    __shared__ f32x4 red[256];
    red[tid] = (f32x4){s,a0,a1,a2};

    // ---------- batch S min/max (144 block entries per image) ----------
    __shared__ float wmn[4], wmx[4];
    float mn = INFINITY, mx = -INFINITY;
    if (tid < 144){
        mn = ws_mm[(b*144+tid)*2+0];
        mx = ws_mm[(b*144+tid)*2+1];
    }
    #pragma unroll
    for (int off=32; off>0; off>>=1){
        mn = fminf(mn, __shfl_xor(mn, off));
        mx = fmaxf(mx, __shfl_xor(mx, off));
    }
    if ((tid & 63) == 0){ wmn[tid>>6]=mn; wmx[tid>>6]=mx; }
    __syncthreads();

    if (tid < 64){
        mn = fminf(fminf(wmn[0],wmn[1]), fminf(wmn[2],wmn[3]));
        mx = fmaxf(fmaxf(wmx[0],wmx[1]), fmaxf(wmx[2],wmx[3]));

        f32x4 p0 = red[tid], p1 = red[64+tid], p2 = red[128+tid], p3 = red[192+tid];
        s  = p0.x+p1.x+p2.x+p3.x;
        a0 = p0.y+p1.y+p2.y+p3.y;
        a1 = p0.z+p1.z+p2.z+p3.z;
        a2 = p0.w+p1.w+p2.w+p3.w;
        float invs = 1.0f/s;
        float xa0 = a0*invs, xa1 = a1*invs, xa2 = a2*invs;

        // mlp_out
        float h6[6];
        #pragma unroll
        for (int i=0;i<6;i++){
            float a = mo_w1[i*3+0]*xa0 + mo_w1[i*3+1]*xa1 + mo_w1[i*3+2]*xa2 + mo_b1[i];
            h6[i] = gelu_tanh(a);
        }
        float y[3];
        #pragma unroll
        for (int i=0;i<3;i++){
            float a = mo_b2[i];
            #pragma unroll
            for (int k=0;k<6;k++) a += mo_w2[i*6+k]*h6[k];
            y[i]=a;
        }
        float m  = (y[0]+y[1]+y[2])*(1.0f/3.0f);
        float d0 = y[0]-m, d1 = y[1]-m, d2 = y[2]-m;
        float var = (d0*d0+d1*d1+d2*d2)*(1.0f/3.0f);
        float inv = 1.0f/sqrtf(var+1e-5f);
        float t0 = d0*inv*n2_g[0]+n2_b[0];
        float t1 = d1*inv*n2_g[1]+n2_b[1];
        float t2 = d2*inv*n2_g[2]+n2_b[2];

        // PSF: S_n normalize + blend
        float4 e  = ((const float4*)ws_eehs)[pix*2+0];   // EE, S
        float4 hh = ((const float4*)ws_eehs)[pix*2+1];   // HH
        float Sn = (e.w - mn)/(mx - mn);
        float f0 = Sn*e.x + (1.0f-Sn)*hh.x;
        float f1 = Sn*e.y + (1.0f-Sn)*hh.y;
        float f2 = Sn*e.z + (1.0f-Sn)*hh.z;

        int pos = pix - b*HW;
        #pragma unroll
        for (int o=0;o<3;o++){
            float val = fuse_b[o]
                      + fuse_w[o*6+0]*t0 + fuse_w[o*6+1]*t1 + fuse_w[o*6+2]*t2
                      + fuse_w[o*6+3]*f0 + fuse_w[o*6+4]*f1 + fuse_w[o*6+5]*f2;
            out[(b*3+o)*HW + pos] = val;
        }
    }
}

extern "C" void kernel_launch(void* const* d_in, const int* in_sizes, int n_in,
                              void* d_out, int out_size, void* d_ws, size_t ws_size,
                              hipStream_t stream) {
    const float* front  = (const float*)d_in[0];
    const float* back   = (const float*)d_in[1];
    // d_in[2] = mask (unused by reference)
    const float* bg     = (const float*)d_in[3];
    const float* mi_w1  = (const float*)d_in[4];
    const float* mi_b1  = (const float*)d_in[5];
    const float* mi_w2  = (const float*)d_in[6];
    const float* mi_b2  = (const float*)d_in[7];
    const float* q_w    = (const float*)d_in[8];
    const float* k_w    = (const float*)d_in[9];
    const float* v_w    = (const float*)d_in[10];
    const float* mo_w1  = (const float*)d_in[11];
    const float* mo_b1  = (const float*)d_in[12];
    const float* mo_w2  = (const float*)d_in[13];
    const float* mo_b2  = (const float*)d_in[14];
    const float* n1_g   = (const float*)d_in[15];
    const float* n1_b   = (const float*)d_in[16];
    const float* n2_g   = (const float*)d_in[17];
    const float* n2_b   = (const float*)d_in[18];
    const float* e_w    = (const float*)d_in[19];
    const float* e_b    = (const float*)d_in[20];
    const float* f_w    = (const float*)d_in[21];
    const float* f_b    = (const float*)d_in[22];
    const float* g_w    = (const float*)d_in[23];
    const float* g_b    = (const float*)d_in[24];
    const float* h_w    = (const float*)d_in[25];
    const float* h_b    = (const float*)d_in[26];
    const float* fuse_w = (const float*)d_in[27];
    const float* fuse_b = (const float*)d_in[28];

    float* ws  = (float*)d_ws;
    float* out = (float*)d_out;

    k1_prep<<<dim3(288), 256, 0, stream>>>(
        front, back, bg, k_w, v_w, mi_w1, mi_b1, mi_w2, mi_b2, q_w,
        n1_g, n1_b, e_w, e_b, f_w, f_b, g_w, g_b, h_w, h_b, ws);

    k2_attn<<<dim3(2304), 256, 0, stream>>>(ws);

    k3_final<8><<<dim3(NPIX/64), 256, 0, stream>>>(
        ws, mo_w1, mo_b1, mo_w2, mo_b2, n2_g, n2_b, fuse_w, fuse_b, out);
}